// Round 2
// baseline (911.540 us; speedup 1.0000x reference)
//
#include <hip/hip_runtime.h>
#include <cstdint>

#define Nn 50000
#define Dd 64
#define Ee 800000
#define NBLK 196          // ceil(Nn/256)
#define FC_BLOCKS 512
#define ND4 (Nn*Dd/4)     // 800000 float4s

__device__ __forceinline__ float relu_f(float v){ return v > 0.f ? v : 0.f; }

// ---- degree histogram (self-loops added later as +1) ----
__global__ __launch_bounds__(256) void k_degree(const int* __restrict__ src, const int* __restrict__ dst,
                                                unsigned* __restrict__ dout, unsigned* __restrict__ din){
    int e = blockIdx.x * 256 + threadIdx.x;
    if (e < Ee){
        atomicAdd(&dout[src[e]], 1u);
        atomicAdd(&din[dst[e]], 1u);
    }
}

__global__ __launch_bounds__(256) void k_norms(const unsigned* __restrict__ dout, const unsigned* __restrict__ din,
                                               float* __restrict__ ns, float* __restrict__ nd){
    int i = blockIdx.x * 256 + threadIdx.x;
    if (i < Nn){
        ns[i] = rsqrtf((float)(dout[i] + 1u));   // +1 = self loop
        nd[i] = rsqrtf((float)(din[i] + 1u));
    }
}

// ---- two-level exclusive scan of deg_in -> CSR offsets ----
__global__ __launch_bounds__(256) void k_blocksum(const unsigned* __restrict__ din, unsigned* __restrict__ bsum){
    __shared__ unsigned s[256];
    int t = threadIdx.x; int i = blockIdx.x * 256 + t;
    s[t] = (i < Nn) ? din[i] : 0u;
    __syncthreads();
    for (int off = 128; off > 0; off >>= 1){ if (t < off) s[t] += s[t + off]; __syncthreads(); }
    if (t == 0) bsum[blockIdx.x] = s[0];
}

__global__ __launch_bounds__(256) void k_scanblocks(const unsigned* __restrict__ bsum, unsigned* __restrict__ boff,
                                                    unsigned* __restrict__ offsets){
    __shared__ unsigned s[256];
    int t = threadIdx.x;
    unsigned v = (t < NBLK) ? bsum[t] : 0u;
    s[t] = v; __syncthreads();
    for (int off = 1; off < 256; off <<= 1){
        unsigned add = (t >= off) ? s[t - off] : 0u;
        __syncthreads();
        s[t] += add;
        __syncthreads();
    }
    boff[t] = s[t] - v;                       // exclusive prefix of block sums
    if (t == 255) offsets[Nn] = s[255];       // total == Ee
}

__global__ __launch_bounds__(256) void k_offsets(const unsigned* __restrict__ din, const unsigned* __restrict__ boff,
                                                 unsigned* __restrict__ offsets, unsigned* __restrict__ cursor){
    __shared__ unsigned s[256];
    int t = threadIdx.x; int i = blockIdx.x * 256 + t;
    unsigned v = (i < Nn) ? din[i] : 0u;
    s[t] = v; __syncthreads();
    for (int off = 1; off < 256; off <<= 1){
        unsigned add = (t >= off) ? s[t - off] : 0u;
        __syncthreads();
        s[t] += add;
        __syncthreads();
    }
    if (i < Nn){
        unsigned val = s[t] - v + boff[blockIdx.x];
        offsets[i] = val;
        cursor[i]  = val;
    }
}

__global__ __launch_bounds__(256) void k_fillcsr(const int* __restrict__ src, const int* __restrict__ dst,
                                                 unsigned* __restrict__ cursor, unsigned* __restrict__ csr){
    int e = blockIdx.x * 256 + threadIdx.x;
    if (e < Ee){
        unsigned pos = atomicAdd(&cursor[dst[e]], 1u);
        csr[pos] = (unsigned)src[e];
    }
}

// ---- h0 = F * norm_src (float4) — only needed for layer 0 input ----
__global__ __launch_bounds__(256) void k_h0(const float* __restrict__ x, const float* __restrict__ ns,
                                            float* __restrict__ h){
    int i = blockIdx.x * 256 + threadIdx.x;   // exactly ND4 threads
    const float4* x4 = (const float4*)x;
    float4* h4 = (float4*)h;
    float s = ns[i >> 4];
    float4 v = x4[i];
    v.x *= s; v.y *= s; v.z *= s; v.w *= s;
    h4[i] = v;
}

// ---- fused layer: gather (SpMM) into LDS tile + 64x64 GEMM + relu (+ns prescale) ----
// Input hin is already ns-prescaled (h = x * norm_src). Output: for layers 0,1
// write relu(y)*ns (prescaled for next layer); for layer 2 write plain relu(y).
__global__ __launch_bounds__(256) void k_layer(const float* __restrict__ hin, const unsigned* __restrict__ offsets,
                                               const unsigned* __restrict__ csr, const float* __restrict__ nd,
                                               const float* __restrict__ ns, const float* __restrict__ W,
                                               const float* __restrict__ bias, float* __restrict__ xout,
                                               int prescale_out){
    __shared__ float As[64 * 65];   // pad 65 -> conflict-free column reads
    __shared__ float Ws[64 * 64];   // W[k][n]
    int t = threadIdx.x;
    int m_base = blockIdx.x * 64;

    // stage weights first (independent of gather; single barrier covers both)
    const float4* W4 = (const float4*)W;
    float4* Ws4 = (float4*)Ws;
    #pragma unroll
    for (int i = 0; i < 4; i++) Ws4[t + 256 * i] = W4[t + 256 * i];

    // gather phase: wave w handles nodes m_base + w*16 .. +15, lane = feature
    int wid = t >> 6, lane = t & 63;
    for (int j = 0; j < 16; j++){
        int m = wid * 16 + j;
        int v = m_base + m;
        float acc = 0.f;
        if (v < Nn){
            acc = hin[(size_t)v * 64 + lane];                 // self loop (already *ns[v])
            unsigned beg = offsets[v], end = offsets[v + 1];
            for (unsigned e = beg; e < end; ++e){
                int s = (int)csr[e];                          // wave-uniform
                acc += hin[(size_t)s * 64 + lane];            // coalesced 256B row
            }
            acc *= nd[v];
        }
        As[m * 65 + lane] = acc;
    }
    __syncthreads();

    // GEMM: 4x4 register blocking, 16x16 thread grid over (m, n)
    int tm = t >> 4, tn = t & 15;
    float acc[4][4];
    #pragma unroll
    for (int i = 0; i < 4; i++)
        #pragma unroll
        for (int j = 0; j < 4; j++) acc[i][j] = 0.f;
    #pragma unroll 4
    for (int k = 0; k < 64; k++){
        float4 w = *(const float4*)&Ws[k * 64 + tn * 4];
        float a[4];
        #pragma unroll
        for (int i = 0; i < 4; i++) a[i] = As[(tm * 4 + i) * 65 + k];
        #pragma unroll
        for (int i = 0; i < 4; i++){
            acc[i][0] += a[i] * w.x;
            acc[i][1] += a[i] * w.y;
            acc[i][2] += a[i] * w.z;
            acc[i][3] += a[i] * w.w;
        }
    }
    float4 b4 = ((const float4*)bias)[tn];
    float4* x4 = (float4*)xout;
    #pragma unroll
    for (int i = 0; i < 4; i++){
        int node = m_base + tm * 4 + i;
        if (node < Nn){
            float4 r;
            r.x = relu_f(acc[i][0] + b4.x);
            r.y = relu_f(acc[i][1] + b4.y);
            r.z = relu_f(acc[i][2] + b4.z);
            r.w = relu_f(acc[i][3] + b4.w);
            if (prescale_out){
                float s = ns[node];   // relu(x)*ns == prescaled h for next layer (ns>0)
                r.x *= s; r.y *= s; r.z *= s; r.w *= s;
            }
            x4[node * 16 + tn] = r;
        }
    }
}

// ---- fc: out[o] = fc_b[o] + sum_i fc_w[o][i]*x[i], 16 partials per thread ----
__global__ __launch_bounds__(256) void k_fc(const float* __restrict__ fcw, const float* __restrict__ x,
                                            float* __restrict__ partials){
    int t = threadIdx.x;
    const float4* x4 = (const float4*)x;
    const float4* w4 = (const float4*)fcw;
    float p[16];
    #pragma unroll
    for (int o = 0; o < 16; o++) p[o] = 0.f;
    for (int i = blockIdx.x * 256 + t; i < ND4; i += FC_BLOCKS * 256){
        float4 xv = x4[i];
        #pragma unroll
        for (int o = 0; o < 16; o++){
            float4 wv = w4[(size_t)o * ND4 + i];
            p[o] += wv.x * xv.x + wv.y * xv.y + wv.z * xv.z + wv.w * xv.w;
        }
    }
    #pragma unroll
    for (int o = 0; o < 16; o++){
        for (int off = 32; off > 0; off >>= 1) p[o] += __shfl_down(p[o], off, 64);
    }
    __shared__ float red[4][16];
    int lane = t & 63, wid = t >> 6;
    if (lane == 0){
        #pragma unroll
        for (int o = 0; o < 16; o++) red[wid][o] = p[o];
    }
    __syncthreads();
    if (t < 16) partials[blockIdx.x * 16 + t] = red[0][t] + red[1][t] + red[2][t] + red[3][t];
}

__global__ __launch_bounds__(256) void k_fc2(const float* __restrict__ partials, const float* __restrict__ fcb,
                                             float* __restrict__ out){
    __shared__ float red[256];
    int t = threadIdx.x; int o = t & 15, j0 = t >> 4;
    float s = 0.f;
    for (int j = j0; j < FC_BLOCKS; j += 16) s += partials[j * 16 + o];
    red[t] = s; __syncthreads();
    for (int off = 128; off >= 16; off >>= 1){ if (t < off) red[t] += red[t + off]; __syncthreads(); }
    if (t < 16) out[t] = red[t] + fcb[t];
}

extern "C" void kernel_launch(void* const* d_in, const int* in_sizes, int n_in,
                              void* d_out, int out_size, void* d_ws, size_t ws_size,
                              hipStream_t stream) {
    const float* F     = (const float*)d_in[0];
    const int*   src   = (const int*)d_in[1];
    const int*   dst   = (const int*)d_in[2];
    const float* gcn_w = (const float*)d_in[3];
    const float* gcn_b = (const float*)d_in[4];
    const float* fc_w  = (const float*)d_in[5];
    const float* fc_b  = (const float*)d_in[6];
    float* out = (float*)d_out;

    char* wsp = (char*)d_ws;
    auto alloc = [&](size_t bytes) -> char* {
        char* p = wsp;
        wsp += (bytes + 255) & ~size_t(255);
        return p;
    };
    unsigned* deg      = (unsigned*)alloc(2 * Nn * 4);   // deg_out | deg_in, one memset
    unsigned* deg_out_ = deg;
    unsigned* deg_in_  = deg + Nn;
    unsigned* offsets  = (unsigned*)alloc((Nn + 1) * 4);
    unsigned* cursor   = (unsigned*)alloc(Nn * 4);
    unsigned* bsum     = (unsigned*)alloc(256 * 4);
    unsigned* boff     = (unsigned*)alloc(256 * 4);
    unsigned* csr      = (unsigned*)alloc(Ee * 4);
    float* norm_src    = (float*)alloc(Nn * 4);
    float* norm_dst    = (float*)alloc(Nn * 4);
    float* partials    = (float*)alloc(FC_BLOCKS * 16 * 4);
    float* bufA        = (float*)alloc((size_t)Nn * 64 * 4);
    float* bufB        = (float*)alloc((size_t)Nn * 64 * 4);

    hipMemsetAsync(deg, 0, 2 * Nn * 4, stream);

    k_degree<<<Ee / 256, 256, 0, stream>>>(src, dst, deg_out_, deg_in_);
    k_norms<<<NBLK, 256, 0, stream>>>(deg_out_, deg_in_, norm_src, norm_dst);
    k_blocksum<<<NBLK, 256, 0, stream>>>(deg_in_, bsum);
    k_scanblocks<<<1, 256, 0, stream>>>(bsum, boff, offsets);
    k_offsets<<<NBLK, 256, 0, stream>>>(deg_in_, boff, offsets, cursor);
    k_fillcsr<<<Ee / 256, 256, 0, stream>>>(src, dst, cursor, csr);

    k_h0<<<ND4 / 256, 256, 0, stream>>>(F, norm_src, bufA);

    int nblk_layer = (Nn + 63) / 64;
    // L0: bufA -> bufB (prescaled), L1: bufB -> bufA (prescaled), L2: bufA -> bufB (plain)
    k_layer<<<nblk_layer, 256, 0, stream>>>(bufA, offsets, csr, norm_dst, norm_src,
                                            gcn_w + 0 * 4096, gcn_b + 0 * 64, bufB, 1);
    k_layer<<<nblk_layer, 256, 0, stream>>>(bufB, offsets, csr, norm_dst, norm_src,
                                            gcn_w + 1 * 4096, gcn_b + 1 * 64, bufA, 1);
    k_layer<<<nblk_layer, 256, 0, stream>>>(bufA, offsets, csr, norm_dst, norm_src,
                                            gcn_w + 2 * 4096, gcn_b + 2 * 64, bufB, 0);

    k_fc<<<FC_BLOCKS, 256, 0, stream>>>(fc_w, bufB, partials);
    k_fc2<<<1, 256, 0, stream>>>(partials, fc_b, out);
}

// Round 3
// 572.831 us; speedup vs baseline: 1.5913x; 1.5913x over previous
//
#include <hip/hip_runtime.h>
#include <cstdint>

#define Nn 50000
#define Dd 64
#define Ee 800000
#define NBLK 196          // ceil(Nn/256)
#define FC_BLOCKS 512
#define ND4 (Nn*Dd/4)     // 800000 float4s

__device__ __forceinline__ float relu_f(float v){ return v > 0.f ? v : 0.f; }

// ---- degree histogram (self-loops added later as +1) ----
__global__ __launch_bounds__(256) void k_degree(const int* __restrict__ src, const int* __restrict__ dst,
                                                unsigned* __restrict__ dout, unsigned* __restrict__ din){
    int e = blockIdx.x * 256 + threadIdx.x;
    if (e < Ee){
        atomicAdd(&dout[src[e]], 1u);
        atomicAdd(&din[dst[e]], 1u);
    }
}

__global__ __launch_bounds__(256) void k_norms(const unsigned* __restrict__ dout, const unsigned* __restrict__ din,
                                               float* __restrict__ ns, float* __restrict__ nd){
    int i = blockIdx.x * 256 + threadIdx.x;
    if (i < Nn){
        ns[i] = rsqrtf((float)(dout[i] + 1u));   // +1 = self loop
        nd[i] = rsqrtf((float)(din[i] + 1u));
    }
}

// ---- two-level exclusive scan of deg_in -> CSR offsets ----
__global__ __launch_bounds__(256) void k_blocksum(const unsigned* __restrict__ din, unsigned* __restrict__ bsum){
    __shared__ unsigned s[256];
    int t = threadIdx.x; int i = blockIdx.x * 256 + t;
    s[t] = (i < Nn) ? din[i] : 0u;
    __syncthreads();
    for (int off = 128; off > 0; off >>= 1){ if (t < off) s[t] += s[t + off]; __syncthreads(); }
    if (t == 0) bsum[blockIdx.x] = s[0];
}

__global__ __launch_bounds__(256) void k_scanblocks(const unsigned* __restrict__ bsum, unsigned* __restrict__ boff,
                                                    unsigned* __restrict__ offsets){
    __shared__ unsigned s[256];
    int t = threadIdx.x;
    unsigned v = (t < NBLK) ? bsum[t] : 0u;
    s[t] = v; __syncthreads();
    for (int off = 1; off < 256; off <<= 1){
        unsigned add = (t >= off) ? s[t - off] : 0u;
        __syncthreads();
        s[t] += add;
        __syncthreads();
    }
    boff[t] = s[t] - v;                       // exclusive prefix of block sums
    if (t == 255) offsets[Nn] = s[255];       // total == Ee
}

__global__ __launch_bounds__(256) void k_offsets(const unsigned* __restrict__ din, const unsigned* __restrict__ boff,
                                                 unsigned* __restrict__ offsets, unsigned* __restrict__ cursor){
    __shared__ unsigned s[256];
    int t = threadIdx.x; int i = blockIdx.x * 256 + t;
    unsigned v = (i < Nn) ? din[i] : 0u;
    s[t] = v; __syncthreads();
    for (int off = 1; off < 256; off <<= 1){
        unsigned add = (t >= off) ? s[t - off] : 0u;
        __syncthreads();
        s[t] += add;
        __syncthreads();
    }
    if (i < Nn){
        unsigned val = s[t] - v + boff[blockIdx.x];
        offsets[i] = val;
        cursor[i]  = val;
    }
}

__global__ __launch_bounds__(256) void k_fillcsr(const int* __restrict__ src, const int* __restrict__ dst,
                                                 unsigned* __restrict__ cursor, unsigned* __restrict__ csr){
    int e = blockIdx.x * 256 + threadIdx.x;
    if (e < Ee){
        unsigned pos = atomicAdd(&cursor[dst[e]], 1u);
        csr[pos] = (unsigned)src[e];
    }
}

// ---- h0 = F * norm_src (float4) — layer-0 input only ----
__global__ __launch_bounds__(256) void k_h0(const float* __restrict__ x, const float* __restrict__ ns,
                                            float* __restrict__ h){
    int i = blockIdx.x * 256 + threadIdx.x;   // exactly ND4 threads
    const float4* x4 = (const float4*)x;
    float4* h4 = (float4*)h;
    float s = ns[i >> 4];
    float4 v = x4[i];
    v.x *= s; v.y *= s; v.z *= s; v.w *= s;
    h4[i] = v;
}

// ---- SpMM gather: one wave per node, 4 edge-groups of 16 lanes (4 edges in
// flight), hand-unroll x2 (8 row-loads in flight). Latency-bound -> maximize
// TLP (50000 waves) and per-wave MLP. ----
__global__ __launch_bounds__(256) void k_gather(const float* __restrict__ h, const unsigned* __restrict__ offsets,
                                                const unsigned* __restrict__ csr, const float* __restrict__ nd,
                                                float* __restrict__ agg){
    int v = blockIdx.x * 4 + (threadIdx.x >> 6);   // 12500 blocks * 4 waves = 50000 nodes
    int lane = threadIdx.x & 63;
    int sub = lane >> 4, sl = lane & 15;           // group 0..3, 16 lanes/group cover a 64-f row
    const float4* h4 = (const float4*)h;

    float4 acc = make_float4(0.f, 0.f, 0.f, 0.f);
    if (sub == 0) acc = h4[(size_t)v * 16 + sl];   // self loop (hin already *ns)

    unsigned beg = offsets[v], end = offsets[v + 1];
    unsigned e = beg + sub;
    // 2 independent chains per group -> 8 outstanding row loads per wave
    for (; e + 4 < end; e += 8){
        int s0 = (int)csr[e];
        int s1 = (int)csr[e + 4];
        float4 r0 = h4[(size_t)s0 * 16 + sl];
        float4 r1 = h4[(size_t)s1 * 16 + sl];
        acc.x += r0.x + r1.x; acc.y += r0.y + r1.y;
        acc.z += r0.z + r1.z; acc.w += r0.w + r1.w;
    }
    if (e < end){
        int s0 = (int)csr[e];
        float4 r0 = h4[(size_t)s0 * 16 + sl];
        acc.x += r0.x; acc.y += r0.y; acc.z += r0.z; acc.w += r0.w;
    }

    // butterfly across the 4 groups (lanes sl, sl+16, sl+32, sl+48)
    acc.x += __shfl_xor(acc.x, 16, 64); acc.y += __shfl_xor(acc.y, 16, 64);
    acc.z += __shfl_xor(acc.z, 16, 64); acc.w += __shfl_xor(acc.w, 16, 64);
    acc.x += __shfl_xor(acc.x, 32, 64); acc.y += __shfl_xor(acc.y, 32, 64);
    acc.z += __shfl_xor(acc.z, 32, 64); acc.w += __shfl_xor(acc.w, 32, 64);

    if (sub == 0){
        float s = nd[v];
        float4 o = make_float4(acc.x * s, acc.y * s, acc.z * s, acc.w * s);
        ((float4*)agg)[(size_t)v * 16 + sl] = o;
    }
}

// ---- x = relu(agg @ W + b) (*ns if prescale_out): 64-node tile, 4x4 reg blocking ----
__global__ __launch_bounds__(256) void k_gemm(const float* __restrict__ agg, const float* __restrict__ W,
                                              const float* __restrict__ bias, const float* __restrict__ ns,
                                              float* __restrict__ xout, int prescale_out){
    __shared__ float As[64 * 65];   // pad 65 -> conflict-free column reads
    __shared__ float Ws[64 * 64];   // W[k][n]
    int t = threadIdx.x;
    int m_base = blockIdx.x * 64;
    const float4* W4   = (const float4*)W;
    float4* Ws4        = (float4*)Ws;
    const float4* agg4 = (const float4*)agg;
    #pragma unroll
    for (int i = 0; i < 4; i++){
        int g = t + 256 * i;              // 1024 float4s
        Ws4[g] = W4[g];
        int m = g >> 4, q = g & 15;
        int node = m_base + m;
        float4 v = make_float4(0.f, 0.f, 0.f, 0.f);
        if (node < Nn) v = agg4[node * 16 + q];
        float* dp = &As[m * 65 + q * 4];
        dp[0] = v.x; dp[1] = v.y; dp[2] = v.z; dp[3] = v.w;
    }
    __syncthreads();
    int tm = t >> 4, tn = t & 15;
    float acc[4][4];
    #pragma unroll
    for (int i = 0; i < 4; i++)
        #pragma unroll
        for (int j = 0; j < 4; j++) acc[i][j] = 0.f;
    #pragma unroll 4
    for (int k = 0; k < 64; k++){
        float4 w = *(const float4*)&Ws[k * 64 + tn * 4];
        float a[4];
        #pragma unroll
        for (int i = 0; i < 4; i++) a[i] = As[(tm * 4 + i) * 65 + k];
        #pragma unroll
        for (int i = 0; i < 4; i++){
            acc[i][0] += a[i] * w.x;
            acc[i][1] += a[i] * w.y;
            acc[i][2] += a[i] * w.z;
            acc[i][3] += a[i] * w.w;
        }
    }
    float4 b4 = ((const float4*)bias)[tn];
    float4* x4 = (float4*)xout;
    #pragma unroll
    for (int i = 0; i < 4; i++){
        int node = m_base + tm * 4 + i;
        if (node < Nn){
            float4 r;
            r.x = relu_f(acc[i][0] + b4.x);
            r.y = relu_f(acc[i][1] + b4.y);
            r.z = relu_f(acc[i][2] + b4.z);
            r.w = relu_f(acc[i][3] + b4.w);
            if (prescale_out){
                float s = ns[node];   // relu(x)*ns == prescaled h for next layer (ns>0)
                r.x *= s; r.y *= s; r.z *= s; r.w *= s;
            }
            x4[node * 16 + tn] = r;
        }
    }
}

// ---- fc: out[o] = fc_b[o] + sum_i fc_w[o][i]*x[i], 16 partials per thread ----
__global__ __launch_bounds__(256) void k_fc(const float* __restrict__ fcw, const float* __restrict__ x,
                                            float* __restrict__ partials){
    int t = threadIdx.x;
    const float4* x4 = (const float4*)x;
    const float4* w4 = (const float4*)fcw;
    float p[16];
    #pragma unroll
    for (int o = 0; o < 16; o++) p[o] = 0.f;
    for (int i = blockIdx.x * 256 + t; i < ND4; i += FC_BLOCKS * 256){
        float4 xv = x4[i];
        #pragma unroll
        for (int o = 0; o < 16; o++){
            float4 wv = w4[(size_t)o * ND4 + i];
            p[o] += wv.x * xv.x + wv.y * xv.y + wv.z * xv.z + wv.w * xv.w;
        }
    }
    #pragma unroll
    for (int o = 0; o < 16; o++){
        for (int off = 32; off > 0; off >>= 1) p[o] += __shfl_down(p[o], off, 64);
    }
    __shared__ float red[4][16];
    int lane = t & 63, wid = t >> 6;
    if (lane == 0){
        #pragma unroll
        for (int o = 0; o < 16; o++) red[wid][o] = p[o];
    }
    __syncthreads();
    if (t < 16) partials[blockIdx.x * 16 + t] = red[0][t] + red[1][t] + red[2][t] + red[3][t];
}

__global__ __launch_bounds__(256) void k_fc2(const float* __restrict__ partials, const float* __restrict__ fcb,
                                             float* __restrict__ out){
    __shared__ float red[256];
    int t = threadIdx.x; int o = t & 15, j0 = t >> 4;
    float s = 0.f;
    for (int j = j0; j < FC_BLOCKS; j += 16) s += partials[j * 16 + o];
    red[t] = s; __syncthreads();
    for (int off = 128; off >= 16; off >>= 1){ if (t < off) red[t] += red[t + off]; __syncthreads(); }
    if (t < 16) out[t] = red[t] + fcb[t];
}

extern "C" void kernel_launch(void* const* d_in, const int* in_sizes, int n_in,
                              void* d_out, int out_size, void* d_ws, size_t ws_size,
                              hipStream_t stream) {
    const float* F     = (const float*)d_in[0];
    const int*   src   = (const int*)d_in[1];
    const int*   dst   = (const int*)d_in[2];
    const float* gcn_w = (const float*)d_in[3];
    const float* gcn_b = (const float*)d_in[4];
    const float* fc_w  = (const float*)d_in[5];
    const float* fc_b  = (const float*)d_in[6];
    float* out = (float*)d_out;

    char* wsp = (char*)d_ws;
    auto alloc = [&](size_t bytes) -> char* {
        char* p = wsp;
        wsp += (bytes + 255) & ~size_t(255);
        return p;
    };
    unsigned* deg      = (unsigned*)alloc(2 * Nn * 4);   // deg_out | deg_in, one memset
    unsigned* deg_out_ = deg;
    unsigned* deg_in_  = deg + Nn;
    unsigned* offsets  = (unsigned*)alloc((Nn + 1) * 4);
    unsigned* cursor   = (unsigned*)alloc(Nn * 4);
    unsigned* bsum     = (unsigned*)alloc(256 * 4);
    unsigned* boff     = (unsigned*)alloc(256 * 4);
    unsigned* csr      = (unsigned*)alloc(Ee * 4);
    float* norm_src    = (float*)alloc(Nn * 4);
    float* norm_dst    = (float*)alloc(Nn * 4);
    float* partials    = (float*)alloc(FC_BLOCKS * 16 * 4);
    float* bufA        = (float*)alloc((size_t)Nn * 64 * 4);
    float* bufB        = (float*)alloc((size_t)Nn * 64 * 4);
    float* aggb        = (float*)alloc((size_t)Nn * 64 * 4);

    hipMemsetAsync(deg, 0, 2 * Nn * 4, stream);

    k_degree<<<Ee / 256, 256, 0, stream>>>(src, dst, deg_out_, deg_in_);
    k_norms<<<NBLK, 256, 0, stream>>>(deg_out_, deg_in_, norm_src, norm_dst);
    k_blocksum<<<NBLK, 256, 0, stream>>>(deg_in_, bsum);
    k_scanblocks<<<1, 256, 0, stream>>>(bsum, boff, offsets);
    k_offsets<<<NBLK, 256, 0, stream>>>(deg_in_, boff, offsets, cursor);
    k_fillcsr<<<Ee / 256, 256, 0, stream>>>(src, dst, cursor, csr);

    k_h0<<<ND4 / 256, 256, 0, stream>>>(F, norm_src, bufA);

    int nblk_gemm = (Nn + 63) / 64;
    // L0: bufA -> bufB (prescaled), L1: bufB -> bufA (prescaled), L2: bufA -> bufB (plain)
    k_gather<<<Nn / 4, 256, 0, stream>>>(bufA, offsets, csr, norm_dst, aggb);
    k_gemm<<<nblk_gemm, 256, 0, stream>>>(aggb, gcn_w + 0 * 4096, gcn_b + 0 * 64, norm_src, bufB, 1);
    k_gather<<<Nn / 4, 256, 0, stream>>>(bufB, offsets, csr, norm_dst, aggb);
    k_gemm<<<nblk_gemm, 256, 0, stream>>>(aggb, gcn_w + 1 * 4096, gcn_b + 1 * 64, norm_src, bufA, 1);
    k_gather<<<Nn / 4, 256, 0, stream>>>(bufA, offsets, csr, norm_dst, aggb);
    k_gemm<<<nblk_gemm, 256, 0, stream>>>(aggb, gcn_w + 2 * 4096, gcn_b + 2 * 64, norm_src, bufB, 0);

    k_fc<<<FC_BLOCKS, 256, 0, stream>>>(fc_w, bufB, partials);
    k_fc2<<<1, 256, 0, stream>>>(partials, fc_b, out);
}

// Round 4
// 558.513 us; speedup vs baseline: 1.6321x; 1.0256x over previous
//
#include <hip/hip_runtime.h>
#include <cstdint>

#define Nn 50000
#define Dd 64
#define Ee 800000
#define NBLK 196          // ceil(Nn/256)
#define FC_BLOCKS 512
#define ND4 (Nn*Dd/4)     // 800000 float4s

__device__ __forceinline__ float relu_f(float v){ return v > 0.f ? v : 0.f; }

// bf16 <-> fp32 (RNE round)
__device__ __forceinline__ unsigned short f2bf(float f){
    unsigned u = __float_as_uint(f);
    u += 0x7fffu + ((u >> 16) & 1u);
    return (unsigned short)(u >> 16);
}
__device__ __forceinline__ float bf2f(unsigned short s){
    return __uint_as_float((unsigned)s << 16);
}
__device__ __forceinline__ float4 bf4_to_f4(ushort4 u){
    return make_float4(bf2f(u.x), bf2f(u.y), bf2f(u.z), bf2f(u.w));
}

// ---- degree histogram (self-loops added later as +1) ----
__global__ __launch_bounds__(256) void k_degree(const int* __restrict__ src, const int* __restrict__ dst,
                                                unsigned* __restrict__ dout, unsigned* __restrict__ din){
    int e = blockIdx.x * 256 + threadIdx.x;
    if (e < Ee){
        atomicAdd(&dout[src[e]], 1u);
        atomicAdd(&din[dst[e]], 1u);
    }
}

__global__ __launch_bounds__(256) void k_norms(const unsigned* __restrict__ dout, const unsigned* __restrict__ din,
                                               float* __restrict__ ns, float* __restrict__ nd){
    int i = blockIdx.x * 256 + threadIdx.x;
    if (i < Nn){
        ns[i] = rsqrtf((float)(dout[i] + 1u));   // +1 = self loop
        nd[i] = rsqrtf((float)(din[i] + 1u));
    }
}

// ---- two-level exclusive scan of deg_in -> CSR offsets ----
__global__ __launch_bounds__(256) void k_blocksum(const unsigned* __restrict__ din, unsigned* __restrict__ bsum){
    __shared__ unsigned s[256];
    int t = threadIdx.x; int i = blockIdx.x * 256 + t;
    s[t] = (i < Nn) ? din[i] : 0u;
    __syncthreads();
    for (int off = 128; off > 0; off >>= 1){ if (t < off) s[t] += s[t + off]; __syncthreads(); }
    if (t == 0) bsum[blockIdx.x] = s[0];
}

__global__ __launch_bounds__(256) void k_scanblocks(const unsigned* __restrict__ bsum, unsigned* __restrict__ boff,
                                                    unsigned* __restrict__ offsets){
    __shared__ unsigned s[256];
    int t = threadIdx.x;
    unsigned v = (t < NBLK) ? bsum[t] : 0u;
    s[t] = v; __syncthreads();
    for (int off = 1; off < 256; off <<= 1){
        unsigned add = (t >= off) ? s[t - off] : 0u;
        __syncthreads();
        s[t] += add;
        __syncthreads();
    }
    boff[t] = s[t] - v;                       // exclusive prefix of block sums
    if (t == 255) offsets[Nn] = s[255];       // total == Ee
}

__global__ __launch_bounds__(256) void k_offsets(const unsigned* __restrict__ din, const unsigned* __restrict__ boff,
                                                 unsigned* __restrict__ offsets, unsigned* __restrict__ cursor){
    __shared__ unsigned s[256];
    int t = threadIdx.x; int i = blockIdx.x * 256 + t;
    unsigned v = (i < Nn) ? din[i] : 0u;
    s[t] = v; __syncthreads();
    for (int off = 1; off < 256; off <<= 1){
        unsigned add = (t >= off) ? s[t - off] : 0u;
        __syncthreads();
        s[t] += add;
        __syncthreads();
    }
    if (i < Nn){
        unsigned val = s[t] - v + boff[blockIdx.x];
        offsets[i] = val;
        cursor[i]  = val;
    }
}

__global__ __launch_bounds__(256) void k_fillcsr(const int* __restrict__ src, const int* __restrict__ dst,
                                                 unsigned* __restrict__ cursor, unsigned* __restrict__ csr){
    int e = blockIdx.x * 256 + threadIdx.x;
    if (e < Ee){
        unsigned pos = atomicAdd(&cursor[dst[e]], 1u);
        csr[pos] = (unsigned)src[e];
    }
}

// ---- h0 = bf16(F * norm_src) — layer-0 input only ----
__global__ __launch_bounds__(256) void k_h0(const float* __restrict__ x, const float* __restrict__ ns,
                                            unsigned short* __restrict__ h){
    int i = blockIdx.x * 256 + threadIdx.x;   // exactly ND4 threads
    const float4* x4 = (const float4*)x;
    float s = ns[i >> 4];
    float4 v = x4[i];
    ushort4 o;
    o.x = f2bf(v.x * s); o.y = f2bf(v.y * s);
    o.z = f2bf(v.z * s); o.w = f2bf(v.w * s);
    ((ushort4*)h)[i] = o;
}

// ---- SpMM gather over bf16 h: one wave per node, 4 edge-groups of 16 lanes,
// x2 unroll (8 rows in flight). h row = 128B. Accumulate fp32. ----
__global__ __launch_bounds__(256) void k_gather(const unsigned short* __restrict__ h,
                                                const unsigned* __restrict__ offsets,
                                                const unsigned* __restrict__ csr, const float* __restrict__ nd,
                                                float* __restrict__ agg){
    int v = blockIdx.x * 4 + (threadIdx.x >> 6);   // 12500 blocks * 4 waves = 50000 nodes
    int lane = threadIdx.x & 63;
    int sub = lane >> 4, sl = lane & 15;           // group 0..3, 16 lanes/group cover a row
    const ushort4* h4 = (const ushort4*)h;         // 16 ushort4 per 64-elem row

    float4 acc = make_float4(0.f, 0.f, 0.f, 0.f);
    if (sub == 0) acc = bf4_to_f4(h4[(size_t)v * 16 + sl]);   // self loop (already *ns)

    unsigned beg = offsets[v], end = offsets[v + 1];
    unsigned e = beg + sub;
    for (; e + 4 < end; e += 8){
        int s0 = (int)csr[e];
        int s1 = (int)csr[e + 4];
        ushort4 u0 = h4[(size_t)s0 * 16 + sl];
        ushort4 u1 = h4[(size_t)s1 * 16 + sl];
        float4 r0 = bf4_to_f4(u0), r1 = bf4_to_f4(u1);
        acc.x += r0.x + r1.x; acc.y += r0.y + r1.y;
        acc.z += r0.z + r1.z; acc.w += r0.w + r1.w;
    }
    if (e < end){
        float4 r0 = bf4_to_f4(h4[(size_t)((int)csr[e]) * 16 + sl]);
        acc.x += r0.x; acc.y += r0.y; acc.z += r0.z; acc.w += r0.w;
    }

    // butterfly across the 4 groups (lanes sl, sl+16, sl+32, sl+48)
    acc.x += __shfl_xor(acc.x, 16, 64); acc.y += __shfl_xor(acc.y, 16, 64);
    acc.z += __shfl_xor(acc.z, 16, 64); acc.w += __shfl_xor(acc.w, 16, 64);
    acc.x += __shfl_xor(acc.x, 32, 64); acc.y += __shfl_xor(acc.y, 32, 64);
    acc.z += __shfl_xor(acc.z, 32, 64); acc.w += __shfl_xor(acc.w, 32, 64);

    if (sub == 0){
        float s = nd[v];
        ((float4*)agg)[(size_t)v * 16 + sl] = make_float4(acc.x * s, acc.y * s, acc.z * s, acc.w * s);
    }
}

// ---- y = relu(agg @ W + b); out either bf16(y*ns) (layers 0,1) or fp32 y (layer 2) ----
__global__ __launch_bounds__(256) void k_gemm(const float* __restrict__ agg, const float* __restrict__ W,
                                              const float* __restrict__ bias, const float* __restrict__ ns,
                                              void* __restrict__ xout, int bf16_prescale_out){
    __shared__ float As[64 * 65];   // pad 65 -> conflict-free column reads
    __shared__ float Ws[64 * 64];   // W[k][n]
    int t = threadIdx.x;
    int m_base = blockIdx.x * 64;
    const float4* W4   = (const float4*)W;
    float4* Ws4        = (float4*)Ws;
    const float4* agg4 = (const float4*)agg;
    #pragma unroll
    for (int i = 0; i < 4; i++){
        int g = t + 256 * i;              // 1024 float4s
        Ws4[g] = W4[g];
        int m = g >> 4, q = g & 15;
        int node = m_base + m;
        float4 v = make_float4(0.f, 0.f, 0.f, 0.f);
        if (node < Nn) v = agg4[node * 16 + q];
        float* dp = &As[m * 65 + q * 4];
        dp[0] = v.x; dp[1] = v.y; dp[2] = v.z; dp[3] = v.w;
    }
    __syncthreads();
    int tm = t >> 4, tn = t & 15;
    float acc[4][4];
    #pragma unroll
    for (int i = 0; i < 4; i++)
        #pragma unroll
        for (int j = 0; j < 4; j++) acc[i][j] = 0.f;
    #pragma unroll 4
    for (int k = 0; k < 64; k++){
        float4 w = *(const float4*)&Ws[k * 64 + tn * 4];
        float a[4];
        #pragma unroll
        for (int i = 0; i < 4; i++) a[i] = As[(tm * 4 + i) * 65 + k];
        #pragma unroll
        for (int i = 0; i < 4; i++){
            acc[i][0] += a[i] * w.x;
            acc[i][1] += a[i] * w.y;
            acc[i][2] += a[i] * w.z;
            acc[i][3] += a[i] * w.w;
        }
    }
    float4 b4 = ((const float4*)bias)[tn];
    #pragma unroll
    for (int i = 0; i < 4; i++){
        int node = m_base + tm * 4 + i;
        if (node < Nn){
            float4 r;
            r.x = relu_f(acc[i][0] + b4.x);
            r.y = relu_f(acc[i][1] + b4.y);
            r.z = relu_f(acc[i][2] + b4.z);
            r.w = relu_f(acc[i][3] + b4.w);
            if (bf16_prescale_out){
                float s = ns[node];   // relu(x)*ns == prescaled h for next layer (ns>0)
                ushort4 o;
                o.x = f2bf(r.x * s); o.y = f2bf(r.y * s);
                o.z = f2bf(r.z * s); o.w = f2bf(r.w * s);
                ((ushort4*)xout)[node * 16 + tn] = o;
            } else {
                ((float4*)xout)[node * 16 + tn] = r;
            }
        }
    }
}

// ---- fc: out[o] = fc_b[o] + sum_i fc_w[o][i]*x[i], 16 partials per thread ----
__global__ __launch_bounds__(256) void k_fc(const float* __restrict__ fcw, const float* __restrict__ x,
                                            float* __restrict__ partials){
    int t = threadIdx.x;
    const float4* x4 = (const float4*)x;
    const float4* w4 = (const float4*)fcw;
    float p[16];
    #pragma unroll
    for (int o = 0; o < 16; o++) p[o] = 0.f;
    for (int i = blockIdx.x * 256 + t; i < ND4; i += FC_BLOCKS * 256){
        float4 xv = x4[i];
        #pragma unroll
        for (int o = 0; o < 16; o++){
            float4 wv = w4[(size_t)o * ND4 + i];
            p[o] += wv.x * xv.x + wv.y * xv.y + wv.z * xv.z + wv.w * xv.w;
        }
    }
    #pragma unroll
    for (int o = 0; o < 16; o++){
        for (int off = 32; off > 0; off >>= 1) p[o] += __shfl_down(p[o], off, 64);
    }
    __shared__ float red[4][16];
    int lane = t & 63, wid = t >> 6;
    if (lane == 0){
        #pragma unroll
        for (int o = 0; o < 16; o++) red[wid][o] = p[o];
    }
    __syncthreads();
    if (t < 16) partials[blockIdx.x * 16 + t] = red[0][t] + red[1][t] + red[2][t] + red[3][t];
}

__global__ __launch_bounds__(256) void k_fc2(const float* __restrict__ partials, const float* __restrict__ fcb,
                                             float* __restrict__ out){
    __shared__ float red[256];
    int t = threadIdx.x; int o = t & 15, j0 = t >> 4;
    float s = 0.f;
    for (int j = j0; j < FC_BLOCKS; j += 16) s += partials[j * 16 + o];
    red[t] = s; __syncthreads();
    for (int off = 128; off >= 16; off >>= 1){ if (t < off) red[t] += red[t + off]; __syncthreads(); }
    if (t < 16) out[t] = red[t] + fcb[t];
}

extern "C" void kernel_launch(void* const* d_in, const int* in_sizes, int n_in,
                              void* d_out, int out_size, void* d_ws, size_t ws_size,
                              hipStream_t stream) {
    const float* F     = (const float*)d_in[0];
    const int*   src   = (const int*)d_in[1];
    const int*   dst   = (const int*)d_in[2];
    const float* gcn_w = (const float*)d_in[3];
    const float* gcn_b = (const float*)d_in[4];
    const float* fc_w  = (const float*)d_in[5];
    const float* fc_b  = (const float*)d_in[6];
    float* out = (float*)d_out;

    char* wsp = (char*)d_ws;
    auto alloc = [&](size_t bytes) -> char* {
        char* p = wsp;
        wsp += (bytes + 255) & ~size_t(255);
        return p;
    };
    unsigned* deg      = (unsigned*)alloc(2 * Nn * 4);   // deg_out | deg_in, one memset
    unsigned* deg_out_ = deg;
    unsigned* deg_in_  = deg + Nn;
    unsigned* offsets  = (unsigned*)alloc((Nn + 1) * 4);
    unsigned* cursor   = (unsigned*)alloc(Nn * 4);
    unsigned* bsum     = (unsigned*)alloc(256 * 4);
    unsigned* boff     = (unsigned*)alloc(256 * 4);
    unsigned* csr      = (unsigned*)alloc(Ee * 4);
    float* norm_src    = (float*)alloc(Nn * 4);
    float* norm_dst    = (float*)alloc(Nn * 4);
    float* partials    = (float*)alloc(FC_BLOCKS * 16 * 4);
    unsigned short* hA = (unsigned short*)alloc((size_t)Nn * 64 * 2);   // bf16 h ping
    unsigned short* hB = (unsigned short*)alloc((size_t)Nn * 64 * 2);   // bf16 h pong
    float* aggb        = (float*)alloc((size_t)Nn * 64 * 4);
    float* xf          = (float*)alloc((size_t)Nn * 64 * 4);            // final fp32 x for fc

    hipMemsetAsync(deg, 0, 2 * Nn * 4, stream);

    k_degree<<<Ee / 256, 256, 0, stream>>>(src, dst, deg_out_, deg_in_);
    k_norms<<<NBLK, 256, 0, stream>>>(deg_out_, deg_in_, norm_src, norm_dst);
    k_blocksum<<<NBLK, 256, 0, stream>>>(deg_in_, bsum);
    k_scanblocks<<<1, 256, 0, stream>>>(bsum, boff, offsets);
    k_offsets<<<NBLK, 256, 0, stream>>>(deg_in_, boff, offsets, cursor);
    k_fillcsr<<<Ee / 256, 256, 0, stream>>>(src, dst, cursor, csr);

    k_h0<<<ND4 / 256, 256, 0, stream>>>(F, norm_src, hA);

    int nblk_gemm = (Nn + 63) / 64;
    // L0: hA -> agg -> hB (bf16 prescaled)
    k_gather<<<Nn / 4, 256, 0, stream>>>(hA, offsets, csr, norm_dst, aggb);
    k_gemm<<<nblk_gemm, 256, 0, stream>>>(aggb, gcn_w + 0 * 4096, gcn_b + 0 * 64, norm_src, hB, 1);
    // L1: hB -> agg -> hA (bf16 prescaled)
    k_gather<<<Nn / 4, 256, 0, stream>>>(hB, offsets, csr, norm_dst, aggb);
    k_gemm<<<nblk_gemm, 256, 0, stream>>>(aggb, gcn_w + 1 * 4096, gcn_b + 1 * 64, norm_src, hA, 1);
    // L2: hA -> agg -> xf (fp32 plain)
    k_gather<<<Nn / 4, 256, 0, stream>>>(hA, offsets, csr, norm_dst, aggb);
    k_gemm<<<nblk_gemm, 256, 0, stream>>>(aggb, gcn_w + 2 * 4096, gcn_b + 2 * 64, norm_src, xf, 0);

    k_fc<<<FC_BLOCKS, 256, 0, stream>>>(fc_w, xf, partials);
    k_fc2<<<1, 256, 0, stream>>>(partials, fc_b, out);
}

// Round 5
// 546.705 us; speedup vs baseline: 1.6673x; 1.0216x over previous
//
#include <hip/hip_runtime.h>
#include <cstdint>

#define Nn 50000
#define Dd 64
#define Ee 800000
#define NBLK 196          // ceil(Nn/256)
#define FC_BLOCKS 512
#define ND4 (Nn*Dd/4)     // 800000 float4s

__device__ __forceinline__ float relu_f(float v){ return v > 0.f ? v : 0.f; }

// bf16 <-> fp32 (RNE round)
__device__ __forceinline__ unsigned short f2bf(float f){
    unsigned u = __float_as_uint(f);
    u += 0x7fffu + ((u >> 16) & 1u);
    return (unsigned short)(u >> 16);
}
// accumulate 8 packed bf16 (uint4) into fp32[8]
__device__ __forceinline__ void add_bf8(float* a, uint4 u){
    a[0] += __uint_as_float(u.x << 16);
    a[1] += __uint_as_float(u.x & 0xffff0000u);
    a[2] += __uint_as_float(u.y << 16);
    a[3] += __uint_as_float(u.y & 0xffff0000u);
    a[4] += __uint_as_float(u.z << 16);
    a[5] += __uint_as_float(u.z & 0xffff0000u);
    a[6] += __uint_as_float(u.w << 16);
    a[7] += __uint_as_float(u.w & 0xffff0000u);
}

// ---- degree histogram (self-loops added later as +1) ----
__global__ __launch_bounds__(256) void k_degree(const int* __restrict__ src, const int* __restrict__ dst,
                                                unsigned* __restrict__ dout, unsigned* __restrict__ din){
    int e = blockIdx.x * 256 + threadIdx.x;
    if (e < Ee){
        atomicAdd(&dout[src[e]], 1u);
        atomicAdd(&din[dst[e]], 1u);
    }
}

__global__ __launch_bounds__(256) void k_norms(const unsigned* __restrict__ dout, const unsigned* __restrict__ din,
                                               float* __restrict__ ns, float* __restrict__ nd){
    int i = blockIdx.x * 256 + threadIdx.x;
    if (i < Nn){
        ns[i] = rsqrtf((float)(dout[i] + 1u));   // +1 = self loop
        nd[i] = rsqrtf((float)(din[i] + 1u));
    }
}

// ---- two-level exclusive scan of deg_in -> CSR offsets ----
__global__ __launch_bounds__(256) void k_blocksum(const unsigned* __restrict__ din, unsigned* __restrict__ bsum){
    __shared__ unsigned s[256];
    int t = threadIdx.x; int i = blockIdx.x * 256 + t;
    s[t] = (i < Nn) ? din[i] : 0u;
    __syncthreads();
    for (int off = 128; off > 0; off >>= 1){ if (t < off) s[t] += s[t + off]; __syncthreads(); }
    if (t == 0) bsum[blockIdx.x] = s[0];
}

__global__ __launch_bounds__(256) void k_scanblocks(const unsigned* __restrict__ bsum, unsigned* __restrict__ boff,
                                                    unsigned* __restrict__ offsets){
    __shared__ unsigned s[256];
    int t = threadIdx.x;
    unsigned v = (t < NBLK) ? bsum[t] : 0u;
    s[t] = v; __syncthreads();
    for (int off = 1; off < 256; off <<= 1){
        unsigned add = (t >= off) ? s[t - off] : 0u;
        __syncthreads();
        s[t] += add;
        __syncthreads();
    }
    boff[t] = s[t] - v;                       // exclusive prefix of block sums
    if (t == 255) offsets[Nn] = s[255];       // total == Ee
}

__global__ __launch_bounds__(256) void k_offsets(const unsigned* __restrict__ din, const unsigned* __restrict__ boff,
                                                 unsigned* __restrict__ offsets, unsigned* __restrict__ cursor){
    __shared__ unsigned s[256];
    int t = threadIdx.x; int i = blockIdx.x * 256 + t;
    unsigned v = (i < Nn) ? din[i] : 0u;
    s[t] = v; __syncthreads();
    for (int off = 1; off < 256; off <<= 1){
        unsigned add = (t >= off) ? s[t - off] : 0u;
        __syncthreads();
        s[t] += add;
        __syncthreads();
    }
    if (i < Nn){
        unsigned val = s[t] - v + boff[blockIdx.x];
        offsets[i] = val;
        cursor[i]  = val;
    }
}

__global__ __launch_bounds__(256) void k_fillcsr(const int* __restrict__ src, const int* __restrict__ dst,
                                                 unsigned* __restrict__ cursor, unsigned* __restrict__ csr){
    int e = blockIdx.x * 256 + threadIdx.x;
    if (e < Ee){
        unsigned pos = atomicAdd(&cursor[dst[e]], 1u);
        csr[pos] = (unsigned)src[e];
    }
}

// ---- h0 = bf16(F * norm_src) — layer-0 input only ----
__global__ __launch_bounds__(256) void k_h0(const float* __restrict__ x, const float* __restrict__ ns,
                                            unsigned short* __restrict__ h){
    int i = blockIdx.x * 256 + threadIdx.x;   // exactly ND4 threads
    const float4* x4 = (const float4*)x;
    float s = ns[i >> 4];
    float4 v = x4[i];
    ushort4 o;
    o.x = f2bf(v.x * s); o.y = f2bf(v.y * s);
    o.z = f2bf(v.z * s); o.w = f2bf(v.w * s);
    ((ushort4*)h)[i] = o;
}

// ---- SpMM gather over bf16 h: one wave per node.
// Lane layout: slot = lane>>3 (8 edge slots), sub = lane&7 (16B chunk of row).
// Per iteration 16 rows in flight (8 slots x unroll 2) -> 2x the MLP of R4.
// Latency-bound kernel: time = dependent rounds x latency; avg degree 16 means
// one iteration covers a typical node. ----
__global__ __launch_bounds__(256) void k_gather(const unsigned short* __restrict__ h,
                                                const unsigned* __restrict__ offsets,
                                                const unsigned* __restrict__ csr, const float* __restrict__ nd,
                                                float* __restrict__ agg){
    int v = blockIdx.x * 4 + (threadIdx.x >> 6);   // 12500 blocks * 4 waves
    int lane = threadIdx.x & 63;
    int slot = lane >> 3;          // 0..7 edge slot
    int sub  = lane & 7;           // 0..7 chunk: elems sub*8 .. sub*8+7
    const uint4* h16 = (const uint4*)h;   // 8 uint4 per 128B row

    float acc[8];
    #pragma unroll
    for (int i = 0; i < 8; i++) acc[i] = 0.f;

    unsigned beg = offsets[v], end = offsets[v + 1];

    if (slot == 0){                // self loop: 8 lanes cover the 128B row
        add_bf8(acc, h16[(size_t)v * 8 + sub]);
    }

    unsigned e = beg + slot;
    for (; e + 8 < end; e += 16){
        int s0 = (int)csr[e];
        int s1 = (int)csr[e + 8];
        uint4 u0 = h16[(size_t)s0 * 8 + sub];
        uint4 u1 = h16[(size_t)s1 * 8 + sub];
        add_bf8(acc, u0);
        add_bf8(acc, u1);
    }
    if (e < end){
        add_bf8(acc, h16[(size_t)((int)csr[e]) * 8 + sub]);
    }

    // reduce over slots (lane bits 3..5): 3 butterfly rounds
    #pragma unroll
    for (int i = 0; i < 8; i++) acc[i] += __shfl_xor(acc[i], 8, 64);
    #pragma unroll
    for (int i = 0; i < 8; i++) acc[i] += __shfl_xor(acc[i], 16, 64);
    #pragma unroll
    for (int i = 0; i < 8; i++) acc[i] += __shfl_xor(acc[i], 32, 64);

    if (slot == 0){
        float s = nd[v];
        float4* aggp = (float4*)agg;
        float4 o0 = make_float4(acc[0] * s, acc[1] * s, acc[2] * s, acc[3] * s);
        float4 o1 = make_float4(acc[4] * s, acc[5] * s, acc[6] * s, acc[7] * s);
        aggp[(size_t)v * 16 + sub * 2 + 0] = o0;
        aggp[(size_t)v * 16 + sub * 2 + 1] = o1;
    }
}

// ---- y = relu(agg @ W + b); out either bf16(y*ns) (layers 0,1) or fp32 y (layer 2) ----
__global__ __launch_bounds__(256) void k_gemm(const float* __restrict__ agg, const float* __restrict__ W,
                                              const float* __restrict__ bias, const float* __restrict__ ns,
                                              void* __restrict__ xout, int bf16_prescale_out){
    __shared__ float As[64 * 65];   // pad 65 -> conflict-free column reads
    __shared__ float Ws[64 * 64];   // W[k][n]
    int t = threadIdx.x;
    int m_base = blockIdx.x * 64;
    const float4* W4   = (const float4*)W;
    float4* Ws4        = (float4*)Ws;
    const float4* agg4 = (const float4*)agg;
    #pragma unroll
    for (int i = 0; i < 4; i++){
        int g = t + 256 * i;              // 1024 float4s
        Ws4[g] = W4[g];
        int m = g >> 4, q = g & 15;
        int node = m_base + m;
        float4 v = make_float4(0.f, 0.f, 0.f, 0.f);
        if (node < Nn) v = agg4[node * 16 + q];
        float* dp = &As[m * 65 + q * 4];
        dp[0] = v.x; dp[1] = v.y; dp[2] = v.z; dp[3] = v.w;
    }
    __syncthreads();
    int tm = t >> 4, tn = t & 15;
    float acc[4][4];
    #pragma unroll
    for (int i = 0; i < 4; i++)
        #pragma unroll
        for (int j = 0; j < 4; j++) acc[i][j] = 0.f;
    #pragma unroll 4
    for (int k = 0; k < 64; k++){
        float4 w = *(const float4*)&Ws[k * 64 + tn * 4];
        float a[4];
        #pragma unroll
        for (int i = 0; i < 4; i++) a[i] = As[(tm * 4 + i) * 65 + k];
        #pragma unroll
        for (int i = 0; i < 4; i++){
            acc[i][0] += a[i] * w.x;
            acc[i][1] += a[i] * w.y;
            acc[i][2] += a[i] * w.z;
            acc[i][3] += a[i] * w.w;
        }
    }
    float4 b4 = ((const float4*)bias)[tn];
    #pragma unroll
    for (int i = 0; i < 4; i++){
        int node = m_base + tm * 4 + i;
        if (node < Nn){
            float4 r;
            r.x = relu_f(acc[i][0] + b4.x);
            r.y = relu_f(acc[i][1] + b4.y);
            r.z = relu_f(acc[i][2] + b4.z);
            r.w = relu_f(acc[i][3] + b4.w);
            if (bf16_prescale_out){
                float s = ns[node];   // relu(x)*ns == prescaled h for next layer (ns>0)
                ushort4 o;
                o.x = f2bf(r.x * s); o.y = f2bf(r.y * s);
                o.z = f2bf(r.z * s); o.w = f2bf(r.w * s);
                ((ushort4*)xout)[node * 16 + tn] = o;
            } else {
                ((float4*)xout)[node * 16 + tn] = r;
            }
        }
    }
}

// ---- fc: out[o] = fc_b[o] + sum_i fc_w[o][i]*x[i], 16 partials per thread ----
__global__ __launch_bounds__(256) void k_fc(const float* __restrict__ fcw, const float* __restrict__ x,
                                            float* __restrict__ partials){
    int t = threadIdx.x;
    const float4* x4 = (const float4*)x;
    const float4* w4 = (const float4*)fcw;
    float p[16];
    #pragma unroll
    for (int o = 0; o < 16; o++) p[o] = 0.f;
    for (int i = blockIdx.x * 256 + t; i < ND4; i += FC_BLOCKS * 256){
        float4 xv = x4[i];
        #pragma unroll
        for (int o = 0; o < 16; o++){
            float4 wv = w4[(size_t)o * ND4 + i];
            p[o] += wv.x * xv.x + wv.y * xv.y + wv.z * xv.z + wv.w * xv.w;
        }
    }
    #pragma unroll
    for (int o = 0; o < 16; o++){
        for (int off = 32; off > 0; off >>= 1) p[o] += __shfl_down(p[o], off, 64);
    }
    __shared__ float red[4][16];
    int lane = t & 63, wid = t >> 6;
    if (lane == 0){
        #pragma unroll
        for (int o = 0; o < 16; o++) red[wid][o] = p[o];
    }
    __syncthreads();
    if (t < 16) partials[blockIdx.x * 16 + t] = red[0][t] + red[1][t] + red[2][t] + red[3][t];
}

__global__ __launch_bounds__(256) void k_fc2(const float* __restrict__ partials, const float* __restrict__ fcb,
                                             float* __restrict__ out){
    __shared__ float red[256];
    int t = threadIdx.x; int o = t & 15, j0 = t >> 4;
    float s = 0.f;
    for (int j = j0; j < FC_BLOCKS; j += 16) s += partials[j * 16 + o];
    red[t] = s; __syncthreads();
    for (int off = 128; off >= 16; off >>= 1){ if (t < off) red[t] += red[t + off]; __syncthreads(); }
    if (t < 16) out[t] = red[t] + fcb[t];
}

extern "C" void kernel_launch(void* const* d_in, const int* in_sizes, int n_in,
                              void* d_out, int out_size, void* d_ws, size_t ws_size,
                              hipStream_t stream) {
    const float* F     = (const float*)d_in[0];
    const int*   src   = (const int*)d_in[1];
    const int*   dst   = (const int*)d_in[2];
    const float* gcn_w = (const float*)d_in[3];
    const float* gcn_b = (const float*)d_in[4];
    const float* fc_w  = (const float*)d_in[5];
    const float* fc_b  = (const float*)d_in[6];
    float* out = (float*)d_out;

    char* wsp = (char*)d_ws;
    auto alloc = [&](size_t bytes) -> char* {
        char* p = wsp;
        wsp += (bytes + 255) & ~size_t(255);
        return p;
    };
    unsigned* deg      = (unsigned*)alloc(2 * Nn * 4);   // deg_out | deg_in, one memset
    unsigned* deg_out_ = deg;
    unsigned* deg_in_  = deg + Nn;
    unsigned* offsets  = (unsigned*)alloc((Nn + 1) * 4);
    unsigned* cursor   = (unsigned*)alloc(Nn * 4);
    unsigned* bsum     = (unsigned*)alloc(256 * 4);
    unsigned* boff     = (unsigned*)alloc(256 * 4);
    unsigned* csr      = (unsigned*)alloc(Ee * 4);
    float* norm_src    = (float*)alloc(Nn * 4);
    float* norm_dst    = (float*)alloc(Nn * 4);
    float* partials    = (float*)alloc(FC_BLOCKS * 16 * 4);
    unsigned short* hA = (unsigned short*)alloc((size_t)Nn * 64 * 2);   // bf16 h ping
    unsigned short* hB = (unsigned short*)alloc((size_t)Nn * 64 * 2);   // bf16 h pong
    float* aggb        = (float*)alloc((size_t)Nn * 64 * 4);
    float* xf          = (float*)alloc((size_t)Nn * 64 * 4);            // final fp32 x for fc

    hipMemsetAsync(deg, 0, 2 * Nn * 4, stream);

    k_degree<<<Ee / 256, 256, 0, stream>>>(src, dst, deg_out_, deg_in_);
    k_norms<<<NBLK, 256, 0, stream>>>(deg_out_, deg_in_, norm_src, norm_dst);
    k_blocksum<<<NBLK, 256, 0, stream>>>(deg_in_, bsum);
    k_scanblocks<<<1, 256, 0, stream>>>(bsum, boff, offsets);
    k_offsets<<<NBLK, 256, 0, stream>>>(deg_in_, boff, offsets, cursor);
    k_fillcsr<<<Ee / 256, 256, 0, stream>>>(src, dst, cursor, csr);

    k_h0<<<ND4 / 256, 256, 0, stream>>>(F, norm_src, hA);

    int nblk_gemm = (Nn + 63) / 64;
    // L0: hA -> agg -> hB (bf16 prescaled)
    k_gather<<<Nn / 4, 256, 0, stream>>>(hA, offsets, csr, norm_dst, aggb);
    k_gemm<<<nblk_gemm, 256, 0, stream>>>(aggb, gcn_w + 0 * 4096, gcn_b + 0 * 64, norm_src, hB, 1);
    // L1: hB -> agg -> hA (bf16 prescaled)
    k_gather<<<Nn / 4, 256, 0, stream>>>(hB, offsets, csr, norm_dst, aggb);
    k_gemm<<<nblk_gemm, 256, 0, stream>>>(aggb, gcn_w + 1 * 4096, gcn_b + 1 * 64, norm_src, hA, 1);
    // L2: hA -> agg -> xf (fp32 plain)
    k_gather<<<Nn / 4, 256, 0, stream>>>(hA, offsets, csr, norm_dst, aggb);
    k_gemm<<<nblk_gemm, 256, 0, stream>>>(aggb, gcn_w + 2 * 4096, gcn_b + 2 * 64, norm_src, xf, 0);

    k_fc<<<FC_BLOCKS, 256, 0, stream>>>(fc_w, xf, partials);
    k_fc2<<<1, 256, 0, stream>>>(partials, fc_b, out);
}